// Round 9
// baseline (1179.520 us; speedup 1.0000x reference)
//
#include <hip/hip_runtime.h>
#include <hip/hip_bf16.h>
#include <math.h>

// Problem constants (B=8, H=W=256, K=11 taps, thresh 0.2)
#define HH 256
#define WW 256
#define HW (HH*WW)
#define BB 8

typedef __hip_bfloat16 bf16;
typedef __attribute__((ext_vector_type(8))) short short8;   // 8 bf16 (4 VGPRs)
typedef __attribute__((ext_vector_type(4))) float f32x4;    // MFMA acc

// async global->LDS, 16B per lane; LDS dest = wave-uniform base + lane*16
typedef __attribute__((address_space(3))) unsigned int lds_uint;
typedef const __attribute__((address_space(1))) unsigned int glob_uint;
__device__ __forceinline__ void dma16(const void* g, void* l) {
    __builtin_amdgcn_global_load_lds((glob_uint*)g, (lds_uint*)l, 16, 0, 0);
}

// Slab: [6 rows][66 px][32 ch] bf16, 64 B per px. Linear unit u (16 B) =
// (row*66+px)*4 + slot. XOR swizzle: LDS slot s of pixel px holds global
// channel-octet seg = s ^ (px&3)  -> wave64 b128 reads hit every bank
// exactly 8x (conflict-free minimum). DMA writes are unit-linear (minimal).
#define SLAB_ELEMS (6 * 66 * 32)
#define SLAB_UNITS 1584

// ---------------------------------------------------------------------------
// Weight reorder: OIHW f32 -> [t][co][ci] bf16 (t = ky*3+kx)
// ---------------------------------------------------------------------------
template<int CO, int CI>
__global__ __launch_bounds__(256) void reorder_w(const float* __restrict__ w,
                                                 bf16* __restrict__ wr)
{
    int idx = blockIdx.x * 256 + threadIdx.x;
    if (idx >= 9 * CO * CI) return;
    int ci = idx % CI;
    int co = (idx / CI) % CO;
    int t  = idx / (CI * CO);
    wr[idx] = __float2bfloat16(w[((size_t)co * CI + ci) * 9 + t]);
}

// Both head weights -> one [9][32][64] bf16 buffer: co 0..10 = wh, 16..26 = wv,
// rest zero-padded.
__global__ __launch_bounds__(256) void reorder_w_head2(const float* __restrict__ wh,
                                                       const float* __restrict__ wv,
                                                       bf16* __restrict__ wr)
{
    int idx = blockIdx.x * 256 + threadIdx.x;
    if (idx >= 9 * 32 * 64) return;
    int ci = idx % 64;
    int co = (idx / 64) % 32;
    int t  = idx / (64 * 32);
    const float* src = (co < 16) ? wh : wv;
    int c = co & 15;
    float v = (c < 11) ? src[((size_t)c * 64 + ci) * 9 + t] : 0.0f;
    wr[idx] = __float2bfloat16(v);
}

// ---------------------------------------------------------------------------
// Pre-zero OOB halo units of the (single) slab; DMA never touches them.
// ---------------------------------------------------------------------------
__device__ __forceinline__ void zero_halo1(bf16* slab, int tid, int x0, int y0)
{
    const short8 z8 = {0,0,0,0,0,0,0,0};
    for (int e = tid; e < SLAB_UNITS; e += 256) {
        int row = e / 264, rem = e - row * 264;
        int px = rem >> 2;
        int yy = y0 - 1 + row, xx = x0 - 1 + px;
        if (yy < 0 || yy >= HH || xx < 0 || xx >= WW)
            *(short8*)(slab + e * 8) = z8;
    }
}

// All 4 waves cooperatively DMA one 32-ch chunk (<=7 instrs/wave -> small
// per-wave vmcnt drain at the following barrier).
template<int CIN>
__device__ __forceinline__ void dma_stage_all(const bf16* in_i, bf16* slab,
                                              int wv, int lane, int x0, int y0, int k0)
{
#pragma unroll
    for (int it = 0; it < 7; ++it) {
        const int ub = it * 256 + wv * 64;       // wave-uniform LDS unit base
        const int u  = ub + lane;
        int row = u / 264, rem = u - row * 264;
        int px = rem >> 2, slot = rem & 3;
        int seg = slot ^ (px & 3);
        int yy = y0 - 1 + row, xx = x0 - 1 + px;
        bool val = (u < SLAB_UNITS) && (yy >= 0) && (yy < HH) && (xx >= 0) && (xx < WW);
        const bf16* g = in_i + ((size_t)(yy * WW + xx)) * CIN + k0 + seg * 8;
        bf16* l = slab + (size_t)ub * 8;
        if (val) dma16(g, l);
    }
}

// ---------------------------------------------------------------------------
// conv1: 3x3 conv over concat(rgb,depth) [4ch f32 planar], ReLU,
// output NHWC bf16 [G][HW][64]. blockIdx.y = img*64 + ytile.
// ---------------------------------------------------------------------------
template<int COC>
__global__ __launch_bounds__(256) void conv3x3_first(const float* __restrict__ rgb,
                                                     const float* __restrict__ depth,
                                                     const float* __restrict__ w,
                                                     const float* __restrict__ bias,
                                                     bf16* __restrict__ out, int b0)
{
    const int tid = threadIdx.x;
    const int img = blockIdx.y >> 6;
    const int b   = b0 + img;
    const int x = blockIdx.x * 64 + (tid & 63);
    const int y = (blockIdx.y & 63) * 4 + (tid >> 6);
    const int cog = blockIdx.z * COC;

    const bool vy0 = (y > 0), vy2 = (y < HH - 1);
    const bool vx0 = (x > 0), vx2 = (x < WW - 1);
    bool val[9];
    int  off[9];
    {
        int t = 0;
        for (int dy = -1; dy <= 1; ++dy)
            for (int dx = -1; dx <= 1; ++dx) {
                val[t] = (dy < 0 ? vy0 : (dy > 0 ? vy2 : true)) &&
                         (dx < 0 ? vx0 : (dx > 0 ? vx2 : true));
                off[t] = dy * WW + dx;
                ++t;
            }
    }

    float acc[COC];
#pragma unroll
    for (int j = 0; j < COC; ++j) acc[j] = bias[cog + j];

    const int p0 = y * WW + x;
#pragma unroll
    for (int ci = 0; ci < 4; ++ci) {
        const float* p = (ci < 3) ? (rgb + ((size_t)(b * 3 + ci)) * HW + p0)
                                  : (depth + (size_t)b * HW + p0);
        float v[9];
#pragma unroll
        for (int t = 0; t < 9; ++t)
            v[t] = val[t] ? p[off[t]] : 0.0f;

        const float* wp = w + ((size_t)cog * 4 + ci) * 9;
#pragma unroll
        for (int j = 0; j < COC; ++j) {
            const float* wj = wp + (size_t)j * 4 * 9;
#pragma unroll
            for (int t = 0; t < 9; ++t)
                acc[j] = fmaf(wj[t], v[t], acc[j]);
        }
    }

    bf16* op = out + (size_t)img * HW * 64 + (size_t)p0 * 64 + cog;
#pragma unroll
    for (int j = 0; j < COC; ++j)
        op[j] = __float2bfloat16(fmaxf(acc[j], 0.0f));
}

// ---------------------------------------------------------------------------
// MFMA implicit-GEMM 3x3 conv: single XOR-swizzled slab, DMA staging by all
// waves, 2 barriers/chunk, one-tap-ahead B prefetch.
// in : NHWC bf16 [G][HW][CIN]   wr : bf16 [9][COUT][CIN]   out : [G][HW][COUT]
// ---------------------------------------------------------------------------
template<int CIN, int COUT, int NT, int WPB>
__global__ __launch_bounds__(256, WPB) void conv_mfma_dma(const bf16* __restrict__ in,
                                                          const bf16* __restrict__ wr,
                                                          const float* __restrict__ bias,
                                                          bf16* __restrict__ out)
{
    constexpr int NCH = CIN / 32;
    __shared__ bf16 slab[SLAB_ELEMS];        // 25,344 B

    const int tid  = threadIdx.x;
    const int lane = tid & 63;
    const int wv   = tid >> 6;
    const int m    = lane & 15;
    const int q    = lane >> 4;
    const int img  = blockIdx.y >> 6;
    const int x0   = blockIdx.x * 64;
    const int y0   = (blockIdx.y & 63) * 4;
    const int y    = y0 + wv;

    const bf16* in_i  = in  + (size_t)img * HW * CIN;
    bf16*       out_i = out + (size_t)img * HW * COUT;

    zero_halo1(slab, tid, x0, y0);

    f32x4 acc[4][NT];
#pragma unroll
    for (int f = 0; f < 4; ++f)
#pragma unroll
        for (int nt = 0; nt < NT; ++nt)
            acc[f][nt] = (f32x4){0.f, 0.f, 0.f, 0.f};

    for (int kc = 0; kc < NCH; ++kc) {
        const int k0 = kc * 32;
        __syncthreads();                     // readers of previous chunk done
        dma_stage_all<CIN>(in_i, slab, wv, lane, x0, y0, k0);
        __syncthreads();                     // vmcnt drained -> slab resident

        const bf16* wbase = wr + (size_t)m * CIN + k0 + q * 8;
        short8 bcur[NT], bnxt[NT];
#pragma unroll
        for (int nt = 0; nt < NT; ++nt)
            bcur[nt] = *(const short8*)(wbase + (size_t)nt * 16 * CIN);

#pragma unroll
        for (int t = 0; t < 9; ++t) {
            // prefetch next tap's B-fragments (hides L2 weight latency)
            if (t < 8) {
                const bf16* wn = wbase + (size_t)(t + 1) * COUT * CIN;
#pragma unroll
                for (int nt = 0; nt < NT; ++nt)
                    bnxt[nt] = *(const short8*)(wn + (size_t)nt * 16 * CIN);
            }
            const int dy = t / 3 - 1, dx = t % 3 - 1;
            const int row = wv + dy + 1;     // 0..5
            short8 a[4];
#pragma unroll
            for (int f = 0; f < 4; ++f) {
                const int px = f * 16 + m + dx + 1;
                const int slot = q ^ (px & 3);
                a[f] = *(const short8*)(slab + (row * 66 + px) * 32 + slot * 8);
            }
#pragma unroll
            for (int nt = 0; nt < NT; ++nt)
#pragma unroll
                for (int f = 0; f < 4; ++f)
                    acc[f][nt] = __builtin_amdgcn_mfma_f32_16x16x32_bf16(a[f], bcur[nt], acc[f][nt], 0, 0, 0);
#pragma unroll
            for (int nt = 0; nt < NT; ++nt) bcur[nt] = bnxt[nt];
        }
    }

    // Epilogue. C/D layout: col = lane&15 (=co offset), row = q*4 + reg (=pixel).
#pragma unroll
    for (int nt = 0; nt < NT; ++nt) {
        const int co = nt * 16 + m;
        const float bb = bias[co];
#pragma unroll
        for (int f = 0; f < 4; ++f) {
#pragma unroll
            for (int r = 0; r < 4; ++r) {
                const int xp = x0 + f * 16 + q * 4 + r;
                const float v = fmaxf(acc[f][nt][r] + bb, 0.0f);
                out_i[((size_t)y * WW + xp) * COUT + co] = __float2bfloat16(v);
            }
        }
    }
}

// ---------------------------------------------------------------------------
// Merged heads: computes BOTH kh and kv (shared staging, single slab).
// weights [9][32][64] (co 0..15 = wh-padded, 16..31 = wv-padded); per-pixel
// softmax over 11 channels via wave-private padded LDS transpose.
// ---------------------------------------------------------------------------
__global__ __launch_bounds__(256, 2) void head_mfma2(const bf16* __restrict__ in,
                                                     const bf16* __restrict__ wrp,
                                                     const float* __restrict__ bh,
                                                     const float* __restrict__ bv,
                                                     float* __restrict__ kh_base,
                                                     float* __restrict__ kv_base,
                                                     int b0)
{
    __shared__ bf16  slab[SLAB_ELEMS];      // 25,344 B
    __shared__ float smx[4][64][17];        // 17,408 B (wave-private slices)

    const int tid  = threadIdx.x;
    const int lane = tid & 63;
    const int wv   = tid >> 6;
    const int m    = lane & 15;
    const int q    = lane >> 4;
    const int img  = blockIdx.y >> 6;
    const int x0   = blockIdx.x * 64;
    const int y0   = (blockIdx.y & 63) * 4;
    const int y    = y0 + wv;

    const bf16* in_i = in + (size_t)img * HW * 64;

    zero_halo1(slab, tid, x0, y0);

    f32x4 acc[4][2];
#pragma unroll
    for (int f = 0; f < 4; ++f) { acc[f][0] = (f32x4){0.f,0.f,0.f,0.f}; acc[f][1] = (f32x4){0.f,0.f,0.f,0.f}; }

    for (int kc = 0; kc < 2; ++kc) {
        const int k0 = kc * 32;
        __syncthreads();
        dma_stage_all<64>(in_i, slab, wv, lane, x0, y0, k0);
        __syncthreads();

#pragma unroll
        for (int t = 0; t < 9; ++t) {
            const int dy = t / 3 - 1, dx = t % 3 - 1;
            const int row = wv + dy + 1;
            const bf16* wt = wrp + (size_t)t * 32 * 64 + (size_t)m * 64 + k0 + q * 8;
            short8 b0f = *(const short8*)(wt);
            short8 b1f = *(const short8*)(wt + 16 * 64);
#pragma unroll
            for (int f = 0; f < 4; ++f) {
                const int px = f * 16 + m + dx + 1;
                const int slot = q ^ (px & 3);
                short8 a = *(const short8*)(slab + (row * 66 + px) * 32 + slot * 8);
                acc[f][0] = __builtin_amdgcn_mfma_f32_16x16x32_bf16(a, b0f, acc[f][0], 0, 0, 0);
                acc[f][1] = __builtin_amdgcn_mfma_f32_16x16x32_bf16(a, b1f, acc[f][1], 0, 0, 0);
            }
        }
    }

    // two heads sequentially; smx slice is wave-private (no barrier needed)
#pragma unroll
    for (int head = 0; head < 2; ++head) {
        const float* bias = head ? bv : bh;
        const float bb = (m < 11) ? bias[m] : 0.0f;
#pragma unroll
        for (int f = 0; f < 4; ++f)
#pragma unroll
            for (int r = 0; r < 4; ++r)
                smx[wv][f * 16 + q * 4 + r][m] = acc[f][head][r] + bb;

        float v[11];
#pragma unroll
        for (int j = 0; j < 11; ++j) v[j] = smx[wv][lane][j];
        float mx = v[0];
#pragma unroll
        for (int j = 1; j < 11; ++j) mx = fmaxf(mx, v[j]);
        float s = 0.0f;
#pragma unroll
        for (int j = 0; j < 11; ++j) { v[j] = expf(v[j] - mx); s += v[j]; }
        const float inv = 1.0f / s;

        float* op = (head ? kv_base : kh_base) + (size_t)(b0 + img) * 11 * HW
                    + (size_t)y * WW + x0 + lane;
#pragma unroll
        for (int j = 0; j < 11; ++j)
            op[(size_t)j * HW] = v[j] * inv;
    }
}

// ---------------------------------------------------------------------------
// Horizontal separable pass (full batch): h = sum_i kh_i * shift_x(rgb, i-5)
// ---------------------------------------------------------------------------
__global__ __launch_bounds__(256) void hpass(const float* __restrict__ rgb,
                                             const float* __restrict__ kh,
                                             float* __restrict__ h)
{
    int idx = blockIdx.x * 256 + threadIdx.x;     // b*HW + p, total 524288
    int b = idx >> 16;                            // HW = 2^16
    int p = idx & (HW - 1);
    int y = p >> 8;
    int x = p & 255;

    float kw[11];
#pragma unroll
    for (int i = 0; i < 11; ++i) kw[i] = kh[((size_t)(b * 11 + i)) * HW + p];

#pragma unroll
    for (int c = 0; c < 3; ++c) {
        const float* rp = rgb + ((size_t)(b * 3 + c)) * HW + (size_t)y * WW;
        float s = 0.0f;
#pragma unroll
        for (int i = 0; i < 11; ++i) {
            int xx = x + i - 5;
            if (xx >= 0 && xx < WW) s = fmaf(kw[i], rp[xx], s);
        }
        h[((size_t)(b * 3 + c)) * HW + p] = s;
    }
}

// ---------------------------------------------------------------------------
// Vertical pass + depth-mask composite. Writes final, blurred, mask.
// ---------------------------------------------------------------------------
__global__ __launch_bounds__(256) void vpass_compose(const float* __restrict__ h,
                                                     const float* __restrict__ kv,
                                                     const float* __restrict__ rgb,
                                                     const float* __restrict__ depth,
                                                     float* __restrict__ fin,
                                                     float* __restrict__ blur,
                                                     float* __restrict__ masko)
{
    int idx = blockIdx.x * 256 + threadIdx.x;
    int b = idx >> 16;                            // HW = 2^16
    int p = idx & (HW - 1);
    int y = p >> 8;
    int x = p & 255;

    float kw[11];
#pragma unroll
    for (int i = 0; i < 11; ++i) kw[i] = kv[((size_t)(b * 11 + i)) * HW + p];

    float d = depth[idx];
    float mk = (d > 0.2f) ? 1.0f : 0.0f;
    masko[idx] = mk;

#pragma unroll
    for (int c = 0; c < 3; ++c) {
        const float* hp = h + ((size_t)(b * 3 + c)) * HW + x;
        float s = 0.0f;
#pragma unroll
        for (int i = 0; i < 11; ++i) {
            int yy = y + i - 5;
            if (yy >= 0 && yy < HH) s = fmaf(kw[i], hp[(size_t)yy * WW], s);
        }
        size_t o = ((size_t)(b * 3 + c)) * HW + p;
        blur[o] = s;
        fin[o] = mk * rgb[o] + (1.0f - mk) * s;
    }
}

// ---------------------------------------------------------------------------
extern "C" void kernel_launch(void* const* d_in, const int* in_sizes, int n_in,
                              void* d_out, int out_size, void* d_ws, size_t ws_size,
                              hipStream_t stream)
{
    const float* rgb   = (const float*)d_in[0];
    const float* depth = (const float*)d_in[1];
    const float* w1 = (const float*)d_in[2];  const float* b1 = (const float*)d_in[3];
    const float* w2 = (const float*)d_in[4];  const float* b2 = (const float*)d_in[5];
    const float* w3 = (const float*)d_in[6];  const float* b3 = (const float*)d_in[7];
    const float* w4 = (const float*)d_in[8];  const float* b4 = (const float*)d_in[9];
    const float* w5 = (const float*)d_in[10]; const float* b5 = (const float*)d_in[11];
    const float* wh = (const float*)d_in[12]; const float* bh = (const float*)d_in[13];
    const float* wv = (const float*)d_in[14]; const float* bv = (const float*)d_in[15];

    float* out    = (float*)d_out;
    float* fin_o  = out;                    // [8,3,256,256]
    float* blur_o = out + 1572864;          // [8,3,256,256]
    float* kh_o   = out + 3145728;          // [8,11,256,256]
    float* kv_o   = out + 8912896;          // [8,11,256,256]
    float* mask_o = out + 14680064;         // [8,1,256,256]

    // --- Select batch group size G from ws_size (deterministic -> graph-safe).
    const size_t perG = (size_t)HW * 2 * (128 + 64 + 128);   // 41.9 MB per image
    const size_t wsz  = (size_t)1 * 1024 * 1024;
    int G = 1;
    if (ws_size >= 8 * perG + wsz) G = 8;
    else if (ws_size >= 4 * perG + wsz) G = 4;
    else if (ws_size >= 2 * perG + wsz) G = 2;

    char* ws = (char*)d_ws;
    const size_t szA = (size_t)G * HW * 128 * 2;
    const size_t szB = (size_t)G * HW * 64 * 2;
    const size_t szC = (size_t)G * HW * 128 * 2;
    bf16* bufA = (bf16*)ws;
    bf16* bufB = (bf16*)(ws + szA);
    bf16* bufC = (bf16*)(ws + szA + szB);
    float* hbuf = (float*)bufC;              // 6.3 MB <= szC

    bf16* w2r  = (bf16*)(ws + szA + szB + szC);
    bf16* w3r  = w2r + 9 * 64 * 64;
    bf16* w4r  = w3r + 9 * 128 * 64;
    bf16* w5r  = w4r + 9 * 128 * 128;
    bf16* whvr = w5r + 9 * 64 * 128;         // [9][32][64]

    dim3 blk(256);

    // one-time weight reorders (graph-safe: identical work every call)
    reorder_w<64, 64>  <<<dim3((9*64*64   + 255) / 256), blk, 0, stream>>>(w2, w2r);
    reorder_w<128, 64> <<<dim3((9*128*64  + 255) / 256), blk, 0, stream>>>(w3, w3r);
    reorder_w<128, 128><<<dim3((9*128*128 + 255) / 256), blk, 0, stream>>>(w4, w4r);
    reorder_w<64, 128> <<<dim3((9*64*128  + 255) / 256), blk, 0, stream>>>(w5, w5r);
    reorder_w_head2    <<<dim3((9*32*64   + 255) / 256), blk, 0, stream>>>(wh, wv, whvr);

    const int GY = 64 * G;
    for (int b0 = 0; b0 < BB; b0 += G) {
        conv3x3_first<16>           <<<dim3(4, GY, 4), blk, 0, stream>>>(rgb, depth, w1, b1, bufA, b0);
        conv_mfma_dma<64, 64, 4, 4> <<<dim3(4, GY), blk, 0, stream>>>(bufA, w2r, b2, bufB);
        conv_mfma_dma<64, 128, 8, 2><<<dim3(4, GY), blk, 0, stream>>>(bufB, w3r, b3, bufC);
        conv_mfma_dma<128,128, 8, 2><<<dim3(4, GY), blk, 0, stream>>>(bufC, w4r, b4, bufA);
        conv_mfma_dma<128, 64, 4, 4><<<dim3(4, GY), blk, 0, stream>>>(bufA, w5r, b5, bufB);
        head_mfma2                  <<<dim3(4, GY), blk, 0, stream>>>(bufB, whvr, bh, bv, kh_o, kv_o, b0);
    }

    // separable blur + composite (full batch; bufC/f3 dead by now)
    hpass<<<dim3(2048), blk, 0, stream>>>(rgb, kh_o, hbuf);
    vpass_compose<<<dim3(2048), blk, 0, stream>>>(hbuf, kv_o, rgb, depth,
                                                  fin_o, blur_o, mask_o);
}

// Round 10
// 1118.078 us; speedup vs baseline: 1.0550x; 1.0550x over previous
//
#include <hip/hip_runtime.h>
#include <hip/hip_bf16.h>
#include <math.h>

// Problem constants (B=8, H=W=256, K=11 taps, thresh 0.2)
#define HH 256
#define WW 256
#define HW (HH*WW)
#define BB 8

typedef __hip_bfloat16 bf16;
typedef __attribute__((ext_vector_type(8))) short short8;   // 8 bf16 (4 VGPRs)
typedef __attribute__((ext_vector_type(4))) float f32x4;    // MFMA acc

// Slab: [(ROWS+2) rows][66 px][32 ch] bf16, 64 B per px.
// XOR swizzle: LDS slot s of pixel px holds channel-octet seg = s ^ (px&3)
// -> both the staging writes (lane-linear units) and the b128 A-reads
// (slot = q ^ (px&3)) touch every bank exactly 8x = conflict-free minimum.

// ---------------------------------------------------------------------------
// Weight reorder: OIHW f32 -> [t][co][ci] bf16 (t = ky*3+kx)
// ---------------------------------------------------------------------------
template<int CO, int CI>
__global__ __launch_bounds__(256) void reorder_w(const float* __restrict__ w,
                                                 bf16* __restrict__ wr)
{
    int idx = blockIdx.x * 256 + threadIdx.x;
    if (idx >= 9 * CO * CI) return;
    int ci = idx % CI;
    int co = (idx / CI) % CO;
    int t  = idx / (CI * CO);
    wr[idx] = __float2bfloat16(w[((size_t)co * CI + ci) * 9 + t]);
}

// Both head weights -> one [9][32][64] bf16 buffer: co 0..10 = wh, 16..26 = wv.
__global__ __launch_bounds__(256) void reorder_w_head2(const float* __restrict__ wh,
                                                       const float* __restrict__ wv,
                                                       bf16* __restrict__ wr)
{
    int idx = blockIdx.x * 256 + threadIdx.x;
    if (idx >= 9 * 32 * 64) return;
    int ci = idx % 64;
    int co = (idx / 64) % 32;
    int t  = idx / (64 * 32);
    const float* src = (co < 16) ? wh : wv;
    int c = co & 15;
    float v = (c < 11) ? src[((size_t)c * 64 + ci) * 9 + t] : 0.0f;
    wr[idx] = __float2bfloat16(v);
}

// ---------------------------------------------------------------------------
// Vector-load staging of one 32-ch chunk into the XOR-swizzled slab.
// OOB lanes write zero (no separate halo pass needed).
// ---------------------------------------------------------------------------
template<int CIN, int ROWS, int TPB>
__device__ __forceinline__ void stage_slab(const bf16* __restrict__ in_i,
                                           bf16* __restrict__ slab,
                                           int tid, int x0, int y0, int k0)
{
    constexpr int UNITS = (ROWS + 2) * 264;      // 16B units
    const short8 z8 = {0,0,0,0,0,0,0,0};
    for (int e = tid; e < UNITS; e += TPB) {
        int row = e / 264, rem = e - row * 264;
        int px = rem >> 2, slot = rem & 3;
        int seg = slot ^ (px & 3);
        int yy = y0 - 1 + row, xx = x0 - 1 + px;
        short8 v = z8;
        if (yy >= 0 && yy < HH && xx >= 0 && xx < WW)
            v = *(const short8*)(in_i + ((size_t)(yy * WW + xx)) * CIN + k0 + seg * 8);
        *(short8*)(slab + (size_t)e * 8) = v;
    }
}

// ---------------------------------------------------------------------------
// conv1: 3x3 conv over concat(rgb,depth) [4ch f32 planar], ReLU,
// output NHWC bf16 [G][HW][64]. blockIdx.y = img*64 + ytile.
// ---------------------------------------------------------------------------
template<int COC>
__global__ __launch_bounds__(256) void conv3x3_first(const float* __restrict__ rgb,
                                                     const float* __restrict__ depth,
                                                     const float* __restrict__ w,
                                                     const float* __restrict__ bias,
                                                     bf16* __restrict__ out, int b0)
{
    const int tid = threadIdx.x;
    const int img = blockIdx.y >> 6;
    const int b   = b0 + img;
    const int x = blockIdx.x * 64 + (tid & 63);
    const int y = (blockIdx.y & 63) * 4 + (tid >> 6);
    const int cog = blockIdx.z * COC;

    const bool vy0 = (y > 0), vy2 = (y < HH - 1);
    const bool vx0 = (x > 0), vx2 = (x < WW - 1);
    bool val[9];
    int  off[9];
    {
        int t = 0;
        for (int dy = -1; dy <= 1; ++dy)
            for (int dx = -1; dx <= 1; ++dx) {
                val[t] = (dy < 0 ? vy0 : (dy > 0 ? vy2 : true)) &&
                         (dx < 0 ? vx0 : (dx > 0 ? vx2 : true));
                off[t] = dy * WW + dx;
                ++t;
            }
    }

    float acc[COC];
#pragma unroll
    for (int j = 0; j < COC; ++j) acc[j] = bias[cog + j];

    const int p0 = y * WW + x;
#pragma unroll
    for (int ci = 0; ci < 4; ++ci) {
        const float* p = (ci < 3) ? (rgb + ((size_t)(b * 3 + ci)) * HW + p0)
                                  : (depth + (size_t)b * HW + p0);
        float v[9];
#pragma unroll
        for (int t = 0; t < 9; ++t)
            v[t] = val[t] ? p[off[t]] : 0.0f;

        const float* wp = w + ((size_t)cog * 4 + ci) * 9;
#pragma unroll
        for (int j = 0; j < COC; ++j) {
            const float* wj = wp + (size_t)j * 4 * 9;
#pragma unroll
            for (int t = 0; t < 9; ++t)
                acc[j] = fmaf(wj[t], v[t], acc[j]);
        }
    }

    bf16* op = out + (size_t)img * HW * 64 + (size_t)p0 * 64 + cog;
#pragma unroll
    for (int j = 0; j < COC; ++j)
        op[j] = __float2bfloat16(fmaxf(acc[j], 0.0f));
}

// ---------------------------------------------------------------------------
// MFMA implicit-GEMM 3x3 conv, retiled: ROWS pixel-rows per block (one wave
// per row, TPB = ROWS*64 threads). Single XOR-swizzled slab staged by vector
// loads; 2 barriers per 32-ch chunk amortized over ROWS*9*NT*4 MFMAs.
// in : NHWC bf16 [G][HW][CIN]   wr : bf16 [9][COUT][CIN]   out : [G][HW][COUT]
// ---------------------------------------------------------------------------
template<int CIN, int COUT, int NT, int ROWS, int TPB, int WPB>
__global__ __launch_bounds__(TPB, WPB) void conv_mfma_v3(const bf16* __restrict__ in,
                                                         const bf16* __restrict__ wr,
                                                         const float* __restrict__ bias,
                                                         bf16* __restrict__ out)
{
    constexpr int NCH = CIN / 32;
    __shared__ bf16 slab[(ROWS + 2) * 66 * 32];

    const int tid  = threadIdx.x;
    const int lane = tid & 63;
    const int wv   = tid >> 6;               // wave = row within tile
    const int m    = lane & 15;
    const int q    = lane >> 4;
    constexpr int YT = HH / ROWS;
    const int img  = blockIdx.y / YT;
    const int x0   = blockIdx.x * 64;
    const int y0   = (blockIdx.y % YT) * ROWS;
    const int y    = y0 + wv;

    const bf16* in_i  = in  + (size_t)img * HW * CIN;
    bf16*       out_i = out + (size_t)img * HW * COUT;

    f32x4 acc[4][NT];
#pragma unroll
    for (int f = 0; f < 4; ++f)
#pragma unroll
        for (int nt = 0; nt < NT; ++nt)
            acc[f][nt] = (f32x4){0.f, 0.f, 0.f, 0.f};

    for (int kc = 0; kc < NCH; ++kc) {
        const int k0 = kc * 32;
        __syncthreads();                     // readers of previous chunk done
        stage_slab<CIN, ROWS, TPB>(in_i, slab, tid, x0, y0, k0);
        __syncthreads();

        const bf16* wbase = wr + (size_t)m * CIN + k0 + q * 8;
#pragma unroll
        for (int t = 0; t < 9; ++t) {
            const int dy = t / 3 - 1, dx = t % 3 - 1;
            const int row = wv + dy + 1;     // 0..ROWS+1
            short8 a[4];
#pragma unroll
            for (int f = 0; f < 4; ++f) {
                const int px = f * 16 + m + dx + 1;
                const int slot = q ^ (px & 3);
                a[f] = *(const short8*)(slab + (row * 66 + px) * 32 + slot * 8);
            }
            const bf16* wt = wbase + (size_t)t * COUT * CIN;
#pragma unroll
            for (int nt = 0; nt < NT; ++nt) {
                short8 bfr = *(const short8*)(wt + (size_t)nt * 16 * CIN);
#pragma unroll
                for (int f = 0; f < 4; ++f)
                    acc[f][nt] = __builtin_amdgcn_mfma_f32_16x16x32_bf16(a[f], bfr, acc[f][nt], 0, 0, 0);
            }
        }
    }

    // Epilogue. C/D layout: col = lane&15 (=co offset), row = q*4 + reg (=pixel).
#pragma unroll
    for (int nt = 0; nt < NT; ++nt) {
        const int co = nt * 16 + m;
        const float bb = bias[co];
#pragma unroll
        for (int f = 0; f < 4; ++f) {
#pragma unroll
            for (int r = 0; r < 4; ++r) {
                const int xp = x0 + f * 16 + q * 4 + r;
                const float v = fmaxf(acc[f][nt][r] + bb, 0.0f);
                out_i[((size_t)y * WW + xp) * COUT + co] = __float2bfloat16(v);
            }
        }
    }
}

// ---------------------------------------------------------------------------
// Merged heads: computes BOTH kh and kv (shared staging, single slab).
// weights [9][32][64] (co 0..15 = wh-padded, 16..31 = wv-padded); per-pixel
// softmax over 11 channels via wave-private padded LDS transpose.
// ---------------------------------------------------------------------------
__global__ __launch_bounds__(256, 2) void head_mfma2(const bf16* __restrict__ in,
                                                     const bf16* __restrict__ wrp,
                                                     const float* __restrict__ bh,
                                                     const float* __restrict__ bv,
                                                     float* __restrict__ kh_base,
                                                     float* __restrict__ kv_base,
                                                     int b0)
{
    __shared__ bf16  slab[6 * 66 * 32];     // 25,344 B
    __shared__ float smx[4][64][17];        // 17,408 B (wave-private slices)

    const int tid  = threadIdx.x;
    const int lane = tid & 63;
    const int wv   = tid >> 6;
    const int m    = lane & 15;
    const int q    = lane >> 4;
    const int img  = blockIdx.y >> 6;
    const int x0   = blockIdx.x * 64;
    const int y0   = (blockIdx.y & 63) * 4;
    const int y    = y0 + wv;

    const bf16* in_i = in + (size_t)img * HW * 64;

    f32x4 acc[4][2];
#pragma unroll
    for (int f = 0; f < 4; ++f) { acc[f][0] = (f32x4){0.f,0.f,0.f,0.f}; acc[f][1] = (f32x4){0.f,0.f,0.f,0.f}; }

    for (int kc = 0; kc < 2; ++kc) {
        const int k0 = kc * 32;
        __syncthreads();
        stage_slab<64, 4, 256>(in_i, slab, tid, x0, y0, k0);
        __syncthreads();

#pragma unroll
        for (int t = 0; t < 9; ++t) {
            const int dy = t / 3 - 1, dx = t % 3 - 1;
            const int row = wv + dy + 1;
            const bf16* wt = wrp + (size_t)t * 32 * 64 + (size_t)m * 64 + k0 + q * 8;
            short8 b0f = *(const short8*)(wt);
            short8 b1f = *(const short8*)(wt + 16 * 64);
#pragma unroll
            for (int f = 0; f < 4; ++f) {
                const int px = f * 16 + m + dx + 1;
                const int slot = q ^ (px & 3);
                short8 a = *(const short8*)(slab + (row * 66 + px) * 32 + slot * 8);
                acc[f][0] = __builtin_amdgcn_mfma_f32_16x16x32_bf16(a, b0f, acc[f][0], 0, 0, 0);
                acc[f][1] = __builtin_amdgcn_mfma_f32_16x16x32_bf16(a, b1f, acc[f][1], 0, 0, 0);
            }
        }
    }

    // two heads sequentially; smx slice is wave-private (no barrier needed)
#pragma unroll
    for (int head = 0; head < 2; ++head) {
        const float* bias = head ? bv : bh;
        const float bb = (m < 11) ? bias[m] : 0.0f;
#pragma unroll
        for (int f = 0; f < 4; ++f)
#pragma unroll
            for (int r = 0; r < 4; ++r)
                smx[wv][f * 16 + q * 4 + r][m] = acc[f][head][r] + bb;

        float v[11];
#pragma unroll
        for (int j = 0; j < 11; ++j) v[j] = smx[wv][lane][j];
        float mx = v[0];
#pragma unroll
        for (int j = 1; j < 11; ++j) mx = fmaxf(mx, v[j]);
        float s = 0.0f;
#pragma unroll
        for (int j = 0; j < 11; ++j) { v[j] = expf(v[j] - mx); s += v[j]; }
        const float inv = 1.0f / s;

        float* op = (head ? kv_base : kh_base) + (size_t)(b0 + img) * 11 * HW
                    + (size_t)y * WW + x0 + lane;
#pragma unroll
        for (int j = 0; j < 11; ++j)
            op[(size_t)j * HW] = v[j] * inv;
    }
}

// ---------------------------------------------------------------------------
// Horizontal separable pass (full batch): h = sum_i kh_i * shift_x(rgb, i-5)
// ---------------------------------------------------------------------------
__global__ __launch_bounds__(256) void hpass(const float* __restrict__ rgb,
                                             const float* __restrict__ kh,
                                             float* __restrict__ h)
{
    int idx = blockIdx.x * 256 + threadIdx.x;     // b*HW + p, total 524288
    int b = idx >> 16;                            // HW = 2^16
    int p = idx & (HW - 1);
    int y = p >> 8;
    int x = p & 255;

    float kw[11];
#pragma unroll
    for (int i = 0; i < 11; ++i) kw[i] = kh[((size_t)(b * 11 + i)) * HW + p];

#pragma unroll
    for (int c = 0; c < 3; ++c) {
        const float* rp = rgb + ((size_t)(b * 3 + c)) * HW + (size_t)y * WW;
        float s = 0.0f;
#pragma unroll
        for (int i = 0; i < 11; ++i) {
            int xx = x + i - 5;
            if (xx >= 0 && xx < WW) s = fmaf(kw[i], rp[xx], s);
        }
        h[((size_t)(b * 3 + c)) * HW + p] = s;
    }
}

// ---------------------------------------------------------------------------
// Vertical pass + depth-mask composite. Writes final, blurred, mask.
// ---------------------------------------------------------------------------
__global__ __launch_bounds__(256) void vpass_compose(const float* __restrict__ h,
                                                     const float* __restrict__ kv,
                                                     const float* __restrict__ rgb,
                                                     const float* __restrict__ depth,
                                                     float* __restrict__ fin,
                                                     float* __restrict__ blur,
                                                     float* __restrict__ masko)
{
    int idx = blockIdx.x * 256 + threadIdx.x;
    int b = idx >> 16;                            // HW = 2^16
    int p = idx & (HW - 1);
    int y = p >> 8;
    int x = p & 255;

    float kw[11];
#pragma unroll
    for (int i = 0; i < 11; ++i) kw[i] = kv[((size_t)(b * 11 + i)) * HW + p];

    float d = depth[idx];
    float mk = (d > 0.2f) ? 1.0f : 0.0f;
    masko[idx] = mk;

#pragma unroll
    for (int c = 0; c < 3; ++c) {
        const float* hp = h + ((size_t)(b * 3 + c)) * HW + x;
        float s = 0.0f;
#pragma unroll
        for (int i = 0; i < 11; ++i) {
            int yy = y + i - 5;
            if (yy >= 0 && yy < HH) s = fmaf(kw[i], hp[(size_t)yy * WW], s);
        }
        size_t o = ((size_t)(b * 3 + c)) * HW + p;
        blur[o] = s;
        fin[o] = mk * rgb[o] + (1.0f - mk) * s;
    }
}

// ---------------------------------------------------------------------------
extern "C" void kernel_launch(void* const* d_in, const int* in_sizes, int n_in,
                              void* d_out, int out_size, void* d_ws, size_t ws_size,
                              hipStream_t stream)
{
    const float* rgb   = (const float*)d_in[0];
    const float* depth = (const float*)d_in[1];
    const float* w1 = (const float*)d_in[2];  const float* b1 = (const float*)d_in[3];
    const float* w2 = (const float*)d_in[4];  const float* b2 = (const float*)d_in[5];
    const float* w3 = (const float*)d_in[6];  const float* b3 = (const float*)d_in[7];
    const float* w4 = (const float*)d_in[8];  const float* b4 = (const float*)d_in[9];
    const float* w5 = (const float*)d_in[10]; const float* b5 = (const float*)d_in[11];
    const float* wh = (const float*)d_in[12]; const float* bh = (const float*)d_in[13];
    const float* wv = (const float*)d_in[14]; const float* bv = (const float*)d_in[15];

    float* out    = (float*)d_out;
    float* fin_o  = out;                    // [8,3,256,256]
    float* blur_o = out + 1572864;          // [8,3,256,256]
    float* kh_o   = out + 3145728;          // [8,11,256,256]
    float* kv_o   = out + 8912896;          // [8,11,256,256]
    float* mask_o = out + 14680064;         // [8,1,256,256]

    // --- Select batch group size G from ws_size (deterministic -> graph-safe).
    const size_t perG = (size_t)HW * 2 * (128 + 64 + 128);   // 41.9 MB per image
    const size_t wsz  = (size_t)1 * 1024 * 1024;
    int G = 1;
    if (ws_size >= 8 * perG + wsz) G = 8;
    else if (ws_size >= 4 * perG + wsz) G = 4;
    else if (ws_size >= 2 * perG + wsz) G = 2;

    char* ws = (char*)d_ws;
    const size_t szA = (size_t)G * HW * 128 * 2;
    const size_t szB = (size_t)G * HW * 64 * 2;
    const size_t szC = (size_t)G * HW * 128 * 2;
    bf16* bufA = (bf16*)ws;
    bf16* bufB = (bf16*)(ws + szA);
    bf16* bufC = (bf16*)(ws + szA + szB);
    float* hbuf = (float*)bufC;              // 6.3 MB <= szC

    bf16* w2r  = (bf16*)(ws + szA + szB + szC);
    bf16* w3r  = w2r + 9 * 64 * 64;
    bf16* w4r  = w3r + 9 * 128 * 64;
    bf16* w5r  = w4r + 9 * 128 * 128;
    bf16* whvr = w5r + 9 * 64 * 128;         // [9][32][64]

    dim3 blk(256);

    // one-time weight reorders (graph-safe: identical work every call)
    reorder_w<64, 64>  <<<dim3((9*64*64   + 255) / 256), blk, 0, stream>>>(w2, w2r);
    reorder_w<128, 64> <<<dim3((9*128*64  + 255) / 256), blk, 0, stream>>>(w3, w3r);
    reorder_w<128, 128><<<dim3((9*128*128 + 255) / 256), blk, 0, stream>>>(w4, w4r);
    reorder_w<64, 128> <<<dim3((9*64*128  + 255) / 256), blk, 0, stream>>>(w5, w5r);
    reorder_w_head2    <<<dim3((9*32*64   + 255) / 256), blk, 0, stream>>>(wh, wv, whvr);

    for (int b0 = 0; b0 < BB; b0 += G) {
        conv3x3_first<16><<<dim3(4, 64 * G, 4), blk, 0, stream>>>(rgb, depth, w1, b1, bufA, b0);
        // COUT=64 layers: 8-row 512-thread blocks (2x work per barrier)
        conv_mfma_v3<64, 64, 4, 8, 512, 4> <<<dim3(4, 32 * G), dim3(512), 0, stream>>>(bufA, w2r, b2, bufB);
        // COUT=128 layers: proven 4-row NT=8 shape
        conv_mfma_v3<64, 128, 8, 4, 256, 2><<<dim3(4, 64 * G), blk, 0, stream>>>(bufB, w3r, b3, bufC);
        conv_mfma_v3<128,128, 8, 4, 256, 2><<<dim3(4, 64 * G), blk, 0, stream>>>(bufC, w4r, b4, bufA);
        conv_mfma_v3<128, 64, 4, 8, 512, 4><<<dim3(4, 32 * G), dim3(512), 0, stream>>>(bufA, w5r, b5, bufB);
        head_mfma2<<<dim3(4, 64 * G), blk, 0, stream>>>(bufB, whvr, bh, bv, kh_o, kv_o, b0);
    }

    // separable blur + composite (full batch; bufC/f3 dead by now)
    hpass<<<dim3(2048), blk, 0, stream>>>(rgb, kh_o, hbuf);
    vpass_compose<<<dim3(2048), blk, 0, stream>>>(hbuf, kv_o, rgb, depth,
                                                  fin_o, blur_o, mask_o);
}